// Round 4
// baseline (250.104 us; speedup 1.0000x reference)
//
#include <hip/hip_runtime.h>

// ---------------------------------------------------------------------------
// GaussianDiffusionTrainer forward:
//   x_t[b,c,h,w] = x0[b,c,h,w] * P[t_b-1] + (h==w ? normal[b,c,h,w] * C[t_b-1] : 0)
// (8192, 3, 32, 32) fp32.  P,C = compile-time constexpr tables (fp32 scan
// matching the reference; sqrt via double Newton).
//
// R2 -> R3/R4: latency-bound fix. One block per 4 images; the tsteps->table
// dependent chain runs once per block (threads 0..3 -> LDS -> regs), then
// 12 unrolled independent float4 iterations per thread. Within-channel f4
// index == tid for every iteration (768 = 3*256), so diagonal predicates
// are loop-invariant.
// ---------------------------------------------------------------------------

constexpr int T_STEPS = 1000;
constexpr int BATCH   = 8192;
constexpr int IMGS_PER_BLOCK = 4;
constexpr int F4_PER_IMG     = 768;            // 3*32*32/4
constexpr int BLOCKS = BATCH / IMGS_PER_BLOCK; // 2048 = 8 per CU, no tail

struct Tables { float P[T_STEPS]; float C[T_STEPS]; };

constexpr double csqrt_d(double x) {
    if (x <= 0.0) return 0.0;
    double scale = 1.0;
    while (x < 0.25) { x *= 4.0;  scale *= 0.5; }
    while (x >= 1.0) { x *= 0.25; scale *= 2.0; }
    double g = 0.5 * (x + 1.0);
    for (int i = 0; i < 40; ++i) {
        double ng = 0.5 * (g + x / g);
        if (ng == g) break;
        g = ng;
    }
    return g * scale;   // scale is a power of two -> exact
}

constexpr Tables make_tables() {
    Tables t{};
    const float beta1 = 1e-4f;
    const float betaT = 0.02f;
    const float delta = (betaT - beta1) / 1000.0f;
    float ac = 1.0f, P = 1.0f, c = 0.0f;
    for (int k = 0; k < T_STEPS; ++k) {
        float beta = beta1 + (float)k * delta;
        ac = ac * (1.0f - beta);
        float s = (float)csqrt_d((double)ac);
        P = P * s;
        c = c * s + beta * beta;
        t.P[k] = P;
        t.C[k] = c;
    }
    return t;
}

__device__ __constant__ Tables d_tbl = make_tables();

__global__ __launch_bounds__(256, 4) void gaussian_diffusion_kernel(
    const float* __restrict__ x0,
    const float* __restrict__ nrm,
    const int*   __restrict__ tsteps,
    float*       __restrict__ out)
{
    __shared__ float2 s_coef[IMGS_PER_BLOCK];

    const int tid = threadIdx.x;
    const int b0  = blockIdx.x * IMGS_PER_BLOCK;

    if (tid < IMGS_PER_BLOCK) {
        int t = tsteps[b0 + tid] - 1;           // in [0, 999]
        s_coef[tid] = make_float2(d_tbl.P[t], d_tbl.C[t]);
    }
    __syncthreads();

    const float2 c0 = s_coef[0];
    const float2 c1 = s_coef[1];
    const float2 c2 = s_coef[2];
    const float2 c3 = s_coef[3];

    // Per-thread, loop-invariant diagonal geometry: within-channel f4 idx == tid.
    const int h  = tid >> 3;            // row 0..31
    const int w0 = (tid & 7) << 2;      // first col of this float4
    const int d  = h - w0;              // diag elem at component d if 0<=d<4
    const bool has_diag = (unsigned)d < 4u;

    const int base = b0 * F4_PER_IMG;   // global f4 base for this block
    const float4* __restrict__ x4 = reinterpret_cast<const float4*>(x0);
    float4*       __restrict__ o4 = reinterpret_cast<float4*>(out);

    #pragma unroll
    for (int j = 0; j < 12; ++j) {
        const int img = j / 3;                       // compile-time per unroll
        const float Pt = (img == 0) ? c0.x : (img == 1) ? c1.x : (img == 2) ? c2.x : c3.x;
        const float Ct = (img == 0) ? c0.y : (img == 1) ? c1.y : (img == 2) ? c2.y : c3.y;

        const int gf4 = base + j * 256 + tid;
        const float4 x = x4[gf4];

        float nv = 0.0f;
        if (has_diag) nv = nrm[(gf4 << 2) + d] * Ct;

        float4 r;
        r.x = x.x * Pt + (d == 0 ? nv : 0.0f);
        r.y = x.y * Pt + (d == 1 ? nv : 0.0f);
        r.z = x.z * Pt + (d == 2 ? nv : 0.0f);
        r.w = x.w * Pt + (d == 3 ? nv : 0.0f);
        o4[gf4] = r;
    }
}

extern "C" void kernel_launch(void* const* d_in, const int* in_sizes, int n_in,
                              void* d_out, int out_size, void* d_ws, size_t ws_size,
                              hipStream_t stream) {
    const float* x0     = (const float*)d_in[0];
    const float* nrm    = (const float*)d_in[1];
    const int*   tsteps = (const int*)d_in[2];
    float*       out    = (float*)d_out;

    gaussian_diffusion_kernel<<<BLOCKS, 256, 0, stream>>>(x0, nrm, tsteps, out);
}